// Round 3
// baseline (169.464 us; speedup 1.0000x reference)
//
#include <hip/hip_runtime.h>
#include <math.h>

#define NCLS   80
#define MTGT   100
#define NANCH  19200   // 3*80*80
#define BATCH  8

__device__ __forceinline__ float fast_rcp(float x) { return __builtin_amdgcn_rcpf(x); }

// Pass 1: per-anchor IoU max/argmax over M targets, BCE, GIoU, inline focal loss
// for positives, per-image partial reductions into accums[b*4 + {bce,pos,bbox,focal}].
__global__ __launch_bounds__(256) void anchor_kernel(
    const float* __restrict__ obj, const float* __restrict__ boxes,
    const float* __restrict__ cls, const float* __restrict__ tb,
    const int* __restrict__ tl, float* __restrict__ accums)
{
    __shared__ float t_lox[MTGT], t_loy[MTGT], t_hix[MTGT], t_hiy[MTGT], t_area[MTGT];
    __shared__ int   t_lab[MTGT];
    const int b   = blockIdx.y;
    const int tid = threadIdx.x;

    if (tid < MTGT) {
        const float4 t = ((const float4*)tb)[b * MTGT + tid];
        t_lox[tid]  = t.x - 0.5f * t.z;
        t_loy[tid]  = t.y - 0.5f * t.w;
        t_hix[tid]  = t.x + 0.5f * t.z;
        t_hiy[tid]  = t.y + 0.5f * t.w;
        t_area[tid] = t.z * t.w;
        t_lab[tid]  = tl[b * MTGT + tid];
    }
    __syncthreads();

    const int i   = blockIdx.x * 256 + tid;   // anchor index within image
    const int gid = b * NANCH + i;

    const float4 bx = ((const float4*)boxes)[gid];
    const float lox = bx.x - 0.5f * bx.z, loy = bx.y - 0.5f * bx.w;
    const float hix = bx.x + 0.5f * bx.z, hiy = bx.y + 0.5f * bx.w;
    const float a1  = bx.z * bx.w;

    float best = -1.0f; int bidx = 0;
    #pragma unroll 4
    for (int m = 0; m < MTGT; ++m) {
        float iw = fminf(hix, t_hix[m]) - fmaxf(lox, t_lox[m]);
        float ih = fminf(hiy, t_hiy[m]) - fmaxf(loy, t_loy[m]);
        iw = fmaxf(iw, 0.0f); ih = fmaxf(ih, 0.0f);
        float inter = iw * ih;
        float uni   = a1 + t_area[m] - inter;
        float iou   = inter * fast_rcp(uni + 1e-6f);
        if (iou > best) { best = iou; bidx = m; }   // first-max semantics (strict >)
    }

    const bool  pos  = (best >= 0.5f);
    const float posf = pos ? 1.0f : 0.0f;

    // objectness BCE (log terms clamped at -100, matching torch BCELoss / reference)
    const float o      = obj[gid];
    const float logp   = fmaxf(logf(o), -100.0f);
    const float log1mp = fmaxf(log1pf(-o), -100.0f);
    const float bce    = -(pos ? logp : log1mp);

    // GIoU bbox loss + focal loss for positives (negatives contribute 0 via posf)
    float bbox_l = 0.0f;
    float focal  = 0.0f;
    if (pos) {
        const int m = bidx;
        float iw = fmaxf(fminf(hix, t_hix[m]) - fmaxf(lox, t_lox[m]), 0.0f);
        float ih = fmaxf(fminf(hiy, t_hiy[m]) - fmaxf(loy, t_loy[m]), 0.0f);
        float inter = iw * ih;
        float uni   = a1 + t_area[m] - inter;
        float iou   = inter * fast_rcp(uni + 1e-6f);
        float ew = fmaxf(fmaxf(hix, t_hix[m]) - fminf(lox, t_lox[m]), 0.0f);
        float eh = fmaxf(fmaxf(hiy, t_hiy[m]) - fminf(loy, t_loy[m]), 0.0f);
        float enc  = ew * eh;
        float giou = iou - (enc - uni) * fast_rcp(enc + 1e-6f);
        bbox_l = 1.0f - giou;

        // focal loss over the positive anchor's class row
        const int ct = t_lab[m];
        const float4* row = (const float4*)(cls + (long)gid * NCLS);
        #pragma unroll
        for (int j4 = 0; j4 < NCLS / 4; ++j4) {
            float4 v = row[j4];
            float xs[4] = { v.x, v.y, v.z, v.w };
            #pragma unroll
            for (int k = 0; k < 4; ++k) {
                const int   j   = j4 * 4 + k;
                const float x   = xs[k];
                const float ax  = fabsf(x);
                const float lse = log1pf(expf(-ax));
                const float ce0 = fmaxf(x, 0.0f) + lse;      // ce when onehot=0
                const float pp  = fast_rcp(1.0f + expf(-x)); // sigmoid(x)
                const float qq  = 1.0f - pp;
                if (j == ct) focal += 0.25f * qq * qq * (ce0 - x);
                else         focal += 0.75f * pp * pp * ce0;
            }
        }
    }

    // block-reduce {bce, posf, bbox_l, focal}
    float v0 = bce, v1 = posf, v2 = bbox_l, v3 = focal;
    #pragma unroll
    for (int off = 32; off; off >>= 1) {
        v0 += __shfl_down(v0, off);
        v1 += __shfl_down(v1, off);
        v2 += __shfl_down(v2, off);
        v3 += __shfl_down(v3, off);
    }
    __shared__ float red[4][4];
    const int wave = tid >> 6, lane = tid & 63;
    if (lane == 0) { red[wave][0] = v0; red[wave][1] = v1; red[wave][2] = v2; red[wave][3] = v3; }
    __syncthreads();
    if (tid == 0) {
        float s0 = 0.f, s1 = 0.f, s2 = 0.f, s3 = 0.f;
        #pragma unroll
        for (int w = 0; w < 4; ++w) {
            s0 += red[w][0]; s1 += red[w][1]; s2 += red[w][2]; s3 += red[w][3];
        }
        atomicAdd(&accums[b * 4 + 0], s0);
        atomicAdd(&accums[b * 4 + 1], s1);
        atomicAdd(&accums[b * 4 + 2], s2);
        atomicAdd(&accums[b * 4 + 3], s3);
    }
}

// Pass 2: combine per-image accumulators into the final scalar (reference formula).
__global__ void finalize_kernel(const float* __restrict__ accums, float* __restrict__ out)
{
    if (threadIdx.x == 0 && blockIdx.x == 0) {
        float sum_pc = 0.f, obj_l = 0.f, bbox_s = 0.f, cls_l = 0.f;
        #pragma unroll
        for (int b = 0; b < BATCH; ++b) {
            const float bce = accums[b * 4 + 0];
            const float pc  = accums[b * 4 + 1];
            const float bb  = accums[b * 4 + 2];
            const float fo  = accums[b * 4 + 3];
            sum_pc += pc;
            obj_l  += bce * (1.0f * pc + 0.5f * ((float)NANCH - pc));
            bbox_s += bb;
            cls_l  += fo / fmaxf(pc * (float)NCLS, 1.0f);
        }
        const float num_pos = fmaxf(sum_pc, 1.0f);
        out[0] = obj_l / (float)BATCH + 5.0f * bbox_s / num_pos + cls_l / (float)BATCH;
    }
}

extern "C" void kernel_launch(void* const* d_in, const int* in_sizes, int n_in,
                              void* d_out, int out_size, void* d_ws, size_t ws_size,
                              hipStream_t stream) {
    const float* obj   = (const float*)d_in[0];
    const float* boxes = (const float*)d_in[1];
    const float* cls   = (const float*)d_in[2];
    const float* tb    = (const float*)d_in[3];
    const int*   tl    = (const int*)d_in[4];
    float* out = (float*)d_out;

    float* accums = (float*)d_ws;                 // 8 images × 4 accumulators

    hipMemsetAsync(d_ws, 0, 128, stream);         // zero accums (ws is poisoned 0xAA)

    dim3 gridA(NANCH / 256, BATCH);
    anchor_kernel<<<gridA, 256, 0, stream>>>(obj, boxes, cls, tb, tl, accums);
    finalize_kernel<<<1, 64, 0, stream>>>(accums, out);
}

// Round 8
// 118.284 us; speedup vs baseline: 1.4327x; 1.4327x over previous
//
#include <hip/hip_runtime.h>
#include <math.h>

#define NCLS   80
#define MTGT   100
#define NANCH  19200   // 3*80*80
#define BATCH  8
#define NBLK   (NANCH / 256)   // 75 blocks per image

__device__ __forceinline__ float fast_rcp(float x) { return __builtin_amdgcn_rcpf(x); }

// focal-loss contribution of one class logit x (matches reference formula exactly)
__device__ __forceinline__ float focal_term(float x, bool is_t) {
    const float ax  = fabsf(x);
    const float q   = __expf(-ax);                        // e^{-|x|} in (0,1]
    const float ce0 = fmaxf(x, 0.0f) + __logf(1.0f + q);  // softplus(x) = ce for onehot=0
    const float r   = fast_rcp(1.0f + q);
    const float p   = (x >= 0.0f) ? r : q * r;            // sigmoid(x)
    const float pt  = is_t ? (1.0f - p) : p;              // 1 - p_t
    const float ce  = is_t ? (ce0 - x) : ce0;
    const float at  = is_t ? 0.25f : 0.75f;
    return at * pt * pt * ce;
}

// Pass 1: per-anchor IoU max/argmax over M targets, BCE, GIoU, ballot-compacted
// focal loss; one float4 partial {bce,pos,bbox,focal} per block (no atomics,
// no workspace zeroing needed — every slot is written every call).
__global__ __launch_bounds__(256) void anchor_kernel(
    const float* __restrict__ obj, const float* __restrict__ boxes,
    const float* __restrict__ cls, const float* __restrict__ tb,
    const int* __restrict__ tl, float4* __restrict__ partials)
{
    __shared__ float4 t_box[MTGT];    // (lo.x, lo.y, hi.x, hi.y)
    __shared__ int    t_lab[MTGT];
    const int b   = blockIdx.y;
    const int tid = threadIdx.x;

    if (tid < MTGT) {
        const float4 t = ((const float4*)tb)[b * MTGT + tid];
        t_box[tid] = make_float4(t.x - 0.5f * t.z, t.y - 0.5f * t.w,
                                 t.x + 0.5f * t.z, t.y + 0.5f * t.w);
        t_lab[tid] = tl[b * MTGT + tid];
    }
    __syncthreads();

    const int i   = blockIdx.x * 256 + tid;   // anchor index within image
    const int gid = b * NANCH + i;

    const float4 bx = ((const float4*)boxes)[gid];
    const float lox = bx.x - 0.5f * bx.z, loy = bx.y - 0.5f * bx.w;
    const float hix = bx.x + 0.5f * bx.z, hiy = bx.y + 0.5f * bx.w;
    const float a1  = bx.z * bx.w;
    const float aa  = a1 + 1e-6f;             // fold union eps

    float best = -1.0f; int bidx = 0;
    #pragma unroll 4
    for (int m = 0; m < MTGT; ++m) {
        const float4 t = t_box[m];
        float iw = fmaxf(fminf(hix, t.z) - fmaxf(lox, t.x), 0.0f);
        float ih = fmaxf(fminf(hiy, t.w) - fmaxf(loy, t.y), 0.0f);
        float inter = iw * ih;
        float area  = (t.z - t.x) * (t.w - t.y);
        float uni   = aa + area - inter;
        float iou   = inter * fast_rcp(uni);
        if (iou > best) { best = iou; bidx = m; }   // first-max (strict >)
    }

    const bool  pos  = (best >= 0.5f);
    const float posf = pos ? 1.0f : 0.0f;

    // objectness BCE: only the branch selected by posf survives; clamp at -100
    const float o   = obj[gid];
    const float bce = -fmaxf(__logf(pos ? o : 1.0f - o), -100.0f);

    // GIoU bbox loss for positives (predicated; rare)
    float bbox_l = 0.0f;
    if (pos) {
        const float4 t = t_box[bidx];
        float iw = fmaxf(fminf(hix, t.z) - fmaxf(lox, t.x), 0.0f);
        float ih = fmaxf(fminf(hiy, t.w) - fmaxf(loy, t.y), 0.0f);
        float inter = iw * ih;
        float area  = (t.z - t.x) * (t.w - t.y);
        float uni   = a1 + area - inter;
        float iou   = inter * fast_rcp(uni + 1e-6f);
        float ew = fmaxf(fmaxf(hix, t.z) - fminf(lox, t.x), 0.0f);
        float eh = fmaxf(fmaxf(hiy, t.w) - fminf(loy, t.y), 0.0f);
        float enc  = ew * eh;
        float giou = iou - (enc - uni) * fast_rcp(enc + 1e-6f);
        bbox_l = 1.0f - giou;
    }

    // ballot-compacted focal loss: all 64 lanes cooperate on each positive anchor
    const int lane = tid & 63;
    const int lab  = t_lab[bidx];             // valid for all lanes (bidx in [0,100))
    float focal = 0.0f;
    unsigned long long pmask = __ballot(pos);
    while (pmask) {
        const int src = __ffsll((long long)pmask) - 1;
        pmask &= pmask - 1;
        const int g = __shfl(gid, src);
        const int c = __shfl(lab, src);
        const float* row = cls + (long)g * NCLS;
        focal += focal_term(row[lane], lane == c);
        if (lane < NCLS - 64) {               // lanes 0..15 cover classes 64..79
            const int j2 = lane + 64;
            focal += focal_term(row[j2], j2 == c);
        }
    }

    // block-reduce {bce, posf, bbox_l, focal}
    float v0 = bce, v1 = posf, v2 = bbox_l, v3 = focal;
    #pragma unroll
    for (int off = 32; off; off >>= 1) {
        v0 += __shfl_down(v0, off);
        v1 += __shfl_down(v1, off);
        v2 += __shfl_down(v2, off);
        v3 += __shfl_down(v3, off);
    }
    __shared__ float red[4][4];
    const int wave = tid >> 6;
    if (lane == 0) { red[wave][0] = v0; red[wave][1] = v1; red[wave][2] = v2; red[wave][3] = v3; }
    __syncthreads();
    if (tid == 0) {
        float s0 = 0.f, s1 = 0.f, s2 = 0.f, s3 = 0.f;
        #pragma unroll
        for (int w = 0; w < 4; ++w) {
            s0 += red[w][0]; s1 += red[w][1]; s2 += red[w][2]; s3 += red[w][3];
        }
        partials[b * NBLK + blockIdx.x] = make_float4(s0, s1, s2, s3);
    }
}

// Pass 2: reduce 75 partials per image (one wave per image), apply reference formula.
__global__ __launch_bounds__(512) void finalize_kernel(
    const float4* __restrict__ partials, float* __restrict__ out)
{
    const int wave = threadIdx.x >> 6;   // image index 0..7
    const int lane = threadIdx.x & 63;

    float s0 = 0.f, s1 = 0.f, s2 = 0.f, s3 = 0.f;
    for (int blk = lane; blk < NBLK; blk += 64) {
        const float4 p = partials[wave * NBLK + blk];
        s0 += p.x; s1 += p.y; s2 += p.z; s3 += p.w;
    }
    #pragma unroll
    for (int off = 32; off; off >>= 1) {
        s0 += __shfl_down(s0, off);
        s1 += __shfl_down(s1, off);
        s2 += __shfl_down(s2, off);
        s3 += __shfl_down(s3, off);
    }
    __shared__ float img[BATCH][4];
    if (lane == 0) { img[wave][0] = s0; img[wave][1] = s1; img[wave][2] = s2; img[wave][3] = s3; }
    __syncthreads();
    if (threadIdx.x == 0) {
        float sum_pc = 0.f, obj_l = 0.f, bbox_s = 0.f, cls_l = 0.f;
        #pragma unroll
        for (int b = 0; b < BATCH; ++b) {
            const float bce = img[b][0];
            const float pc  = img[b][1];
            const float bb  = img[b][2];
            const float fo  = img[b][3];
            sum_pc += pc;
            obj_l  += bce * (1.0f * pc + 0.5f * ((float)NANCH - pc));
            bbox_s += bb;
            cls_l  += fo / fmaxf(pc * (float)NCLS, 1.0f);
        }
        const float num_pos = fmaxf(sum_pc, 1.0f);
        out[0] = obj_l / (float)BATCH + 5.0f * bbox_s / num_pos + cls_l / (float)BATCH;
    }
}

extern "C" void kernel_launch(void* const* d_in, const int* in_sizes, int n_in,
                              void* d_out, int out_size, void* d_ws, size_t ws_size,
                              hipStream_t stream) {
    const float* obj   = (const float*)d_in[0];
    const float* boxes = (const float*)d_in[1];
    const float* cls   = (const float*)d_in[2];
    const float* tb    = (const float*)d_in[3];
    const int*   tl    = (const int*)d_in[4];
    float* out = (float*)d_out;

    float4* partials = (float4*)d_ws;   // 8 images × 75 blocks × float4 = 9.6 KB

    dim3 gridA(NBLK, BATCH);
    anchor_kernel<<<gridA, 256, 0, stream>>>(obj, boxes, cls, tb, tl, partials);
    finalize_kernel<<<1, 512, 0, stream>>>(partials, out);
}

// Round 9
// 117.614 us; speedup vs baseline: 1.4409x; 1.0057x over previous
//
#include <hip/hip_runtime.h>
#include <math.h>

#define NCLS   80
#define MTGT   100
#define NANCH  19200   // 3*80*80
#define BATCH  8
#define BLK    64                 // single-wave blocks
#define NBLK   (NANCH / BLK)      // 300 blocks per image

__device__ __forceinline__ float fast_rcp(float x) { return __builtin_amdgcn_rcpf(x); }

// focal-loss contribution of one class logit x (matches reference formula exactly)
__device__ __forceinline__ float focal_term(float x, bool is_t) {
    const float ax  = fabsf(x);
    const float q   = __expf(-ax);                        // e^{-|x|} in (0,1]
    const float ce0 = fmaxf(x, 0.0f) + __logf(1.0f + q);  // softplus(x) = ce for onehot=0
    const float r   = fast_rcp(1.0f + q);
    const float p   = (x >= 0.0f) ? r : q * r;            // sigmoid(x)
    const float pt  = is_t ? (1.0f - p) : p;              // 1 - p_t
    const float ce  = is_t ? (ce0 - x) : ce0;
    const float at  = is_t ? 0.25f : 0.75f;
    return at * pt * pt * ce;
}

// Pass 1: one wave per 64 anchors. IoU max/argmax over M targets, BCE, GIoU,
// ballot-compacted focal; one float4 partial {bce,pos,bbox,focal} per block.
// No atomics; every partial slot written every call (safe under 0xAA poison).
__global__ __launch_bounds__(BLK) void anchor_kernel(
    const float* __restrict__ obj, const float* __restrict__ boxes,
    const float* __restrict__ cls, const float* __restrict__ tb,
    const int* __restrict__ tl, float4* __restrict__ partials)
{
    __shared__ float4 t_box[MTGT];    // (lo.x, lo.y, hi.x, hi.y)
    __shared__ float  t_area[MTGT];
    __shared__ int    t_lab[MTGT];
    const int b    = blockIdx.y;
    const int lane = threadIdx.x;     // 0..63

    for (int m = lane; m < MTGT; m += BLK) {
        const float4 t = ((const float4*)tb)[b * MTGT + m];
        t_box[m]  = make_float4(t.x - 0.5f * t.z, t.y - 0.5f * t.w,
                                t.x + 0.5f * t.z, t.y + 0.5f * t.w);
        t_area[m] = t.z * t.w;
        t_lab[m]  = tl[b * MTGT + m];
    }
    __syncthreads();

    const int i   = blockIdx.x * BLK + lane;  // anchor index within image
    const int gid = b * NANCH + i;

    const float4 bx = ((const float4*)boxes)[gid];
    const float lox = bx.x - 0.5f * bx.z, loy = bx.y - 0.5f * bx.w;
    const float hix = bx.x + 0.5f * bx.z, hiy = bx.y + 0.5f * bx.w;
    const float a1  = bx.z * bx.w;
    const float aa  = a1 + 1e-6f;             // fold union eps

    float best = -1.0f; int bidx = 0;
    #pragma unroll 10
    for (int m = 0; m < MTGT; ++m) {
        const float4 t = t_box[m];
        float iw = fmaxf(fminf(hix, t.z) - fmaxf(lox, t.x), 0.0f);
        float ih = fmaxf(fminf(hiy, t.w) - fmaxf(loy, t.y), 0.0f);
        float inter = iw * ih;
        float uni   = aa + t_area[m] - inter;
        float iou   = inter * fast_rcp(uni);
        if (iou > best) { best = iou; bidx = m; }   // first-max (strict >)
    }

    const bool  pos  = (best >= 0.5f);
    const float posf = pos ? 1.0f : 0.0f;

    // objectness BCE: only the branch selected by posf survives; clamp at -100
    const float o   = obj[gid];
    const float bce = -fmaxf(__logf(pos ? o : 1.0f - o), -100.0f);

    // GIoU bbox loss for positives (predicated; rare)
    float bbox_l = 0.0f;
    if (pos) {
        const float4 t = t_box[bidx];
        float iw = fmaxf(fminf(hix, t.z) - fmaxf(lox, t.x), 0.0f);
        float ih = fmaxf(fminf(hiy, t.w) - fmaxf(loy, t.y), 0.0f);
        float inter = iw * ih;
        float uni   = a1 + t_area[bidx] - inter;
        float iou   = inter * fast_rcp(uni + 1e-6f);
        float ew = fmaxf(fmaxf(hix, t.z) - fminf(lox, t.x), 0.0f);
        float eh = fmaxf(fmaxf(hiy, t.w) - fminf(loy, t.y), 0.0f);
        float enc  = ew * eh;
        float giou = iou - (enc - uni) * fast_rcp(enc + 1e-6f);
        bbox_l = 1.0f - giou;
    }

    // ballot-compacted focal loss: all 64 lanes cooperate on each positive anchor
    const int lab = t_lab[bidx];              // valid for all lanes
    float focal = 0.0f;
    unsigned long long pmask = __ballot(pos);
    while (pmask) {
        const int src = __ffsll((long long)pmask) - 1;
        pmask &= pmask - 1;
        const int g = __shfl(gid, src);
        const int c = __shfl(lab, src);
        const float* row = cls + (long)g * NCLS;
        focal += focal_term(row[lane], lane == c);
        if (lane < NCLS - 64) {               // lanes 0..15 cover classes 64..79
            const int j2 = lane + 64;
            focal += focal_term(row[j2], j2 == c);
        }
    }

    // wave-reduce {bce, posf, bbox_l, focal}; lane 0 writes the block partial
    float v0 = bce, v1 = posf, v2 = bbox_l, v3 = focal;
    #pragma unroll
    for (int off = 32; off; off >>= 1) {
        v0 += __shfl_down(v0, off);
        v1 += __shfl_down(v1, off);
        v2 += __shfl_down(v2, off);
        v3 += __shfl_down(v3, off);
    }
    if (lane == 0)
        partials[b * NBLK + blockIdx.x] = make_float4(v0, v1, v2, v3);
}

// Pass 2: reduce 300 partials per image (one wave per image), apply reference formula.
__global__ __launch_bounds__(512) void finalize_kernel(
    const float4* __restrict__ partials, float* __restrict__ out)
{
    const int wave = threadIdx.x >> 6;   // image index 0..7
    const int lane = threadIdx.x & 63;

    float s0 = 0.f, s1 = 0.f, s2 = 0.f, s3 = 0.f;
    for (int blk = lane; blk < NBLK; blk += 64) {
        const float4 p = partials[wave * NBLK + blk];
        s0 += p.x; s1 += p.y; s2 += p.z; s3 += p.w;
    }
    #pragma unroll
    for (int off = 32; off; off >>= 1) {
        s0 += __shfl_down(s0, off);
        s1 += __shfl_down(s1, off);
        s2 += __shfl_down(s2, off);
        s3 += __shfl_down(s3, off);
    }
    __shared__ float img[BATCH][4];
    if (lane == 0) { img[wave][0] = s0; img[wave][1] = s1; img[wave][2] = s2; img[wave][3] = s3; }
    __syncthreads();
    if (threadIdx.x == 0) {
        float sum_pc = 0.f, obj_l = 0.f, bbox_s = 0.f, cls_l = 0.f;
        #pragma unroll
        for (int b = 0; b < BATCH; ++b) {
            const float bce = img[b][0];
            const float pc  = img[b][1];
            const float bb  = img[b][2];
            const float fo  = img[b][3];
            sum_pc += pc;
            obj_l  += bce * (1.0f * pc + 0.5f * ((float)NANCH - pc));
            bbox_s += bb;
            cls_l  += fo / fmaxf(pc * (float)NCLS, 1.0f);
        }
        const float num_pos = fmaxf(sum_pc, 1.0f);
        out[0] = obj_l / (float)BATCH + 5.0f * bbox_s / num_pos + cls_l / (float)BATCH;
    }
}

extern "C" void kernel_launch(void* const* d_in, const int* in_sizes, int n_in,
                              void* d_out, int out_size, void* d_ws, size_t ws_size,
                              hipStream_t stream) {
    const float* obj   = (const float*)d_in[0];
    const float* boxes = (const float*)d_in[1];
    const float* cls   = (const float*)d_in[2];
    const float* tb    = (const float*)d_in[3];
    const int*   tl    = (const int*)d_in[4];
    float* out = (float*)d_out;

    float4* partials = (float4*)d_ws;   // 8 images × 300 blocks × float4 = 38.4 KB

    dim3 gridA(NBLK, BATCH);
    anchor_kernel<<<gridA, BLK, 0, stream>>>(obj, boxes, cls, tb, tl, partials);
    finalize_kernel<<<1, 512, 0, stream>>>(partials, out);
}